// Round 7
// baseline (436.666 us; speedup 1.0000x reference)
//
#include <hip/hip_runtime.h>
#include <hip/hip_bf16.h>

// Transducer joint: logits[b,t,u,v] = tanh(enc_proj[b,t,:]+dec_proj[b,u,:]+b1) @ W2 + b2
// B=4 T=256 U=128, ENC=DEC=512, INNER=512, VOCAB=2048
// R7: persistent GEMM. 256 blocks (1/CU), each: ny fixed, 32 my-panel tiles.
//     Stores of tile t-1 spread 1-per-phase through tile t's K-loop (in-order
//     vmcnt ledger includes them). Ring-3 LDS staging, per-wave transpose
//     slices for full-line nt stores, XCD-grouped panel schedule.

typedef __attribute__((ext_vector_type(4))) float f32x4;
typedef __attribute__((ext_vector_type(8))) __bf16 bf16x8;
typedef __attribute__((ext_vector_type(8))) unsigned short u16x8;

__device__ __forceinline__ float bf2f(unsigned short u) {
  unsigned int x = ((unsigned int)u) << 16;
  return __builtin_bit_cast(float, x);
}
__device__ __forceinline__ unsigned short f2bf(float f) {
  unsigned int x = __builtin_bit_cast(unsigned int, f);
  x += 0x7fff + ((x >> 16) & 1);   // RNE
  return (unsigned short)(x >> 16);
}
__device__ __forceinline__ float tanh_fast(float x) {
  float e = __expf(2.0f * x);
  return 1.0f - 2.0f * __builtin_amdgcn_rcpf(e + 1.0f);
}

typedef __attribute__((address_space(3))) unsigned int lds_u32;
typedef const __attribute__((address_space(1))) unsigned int glb_u32;
__device__ __forceinline__ void gl16(const void* g, void* l) {
  __builtin_amdgcn_global_load_lds((glb_u32*)g, (lds_u32*)l, 16, 0, 0);
}

#define BAR __builtin_amdgcn_s_barrier()
#define LGKM0 asm volatile("s_waitcnt lgkmcnt(0)" ::: "memory")
#define VMCNT(n) asm volatile("s_waitcnt vmcnt(" #n ")" ::: "memory")
#define MEMPIN asm volatile("" ::: "memory")

// ---------------- Pass 1: proj (x-in-LDS broadcast GEMM) ----------------
__global__ __launch_bounds__(512) void proj8_kernel(
    const float* __restrict__ enc, const float* __restrict__ dec,
    const float* __restrict__ W1, const float* __restrict__ b1,
    float* __restrict__ enc_proj, unsigned short* __restrict__ decb) {
  __shared__ float xs[8][512];
  const int bid = blockIdx.x;
  const bool isenc = bid < 128;
  const int rows0 = (isenc ? bid : bid - 128) * 8;
  const float* src = (isenc ? enc : dec) + (size_t)rows0 * 512;
  const int tid = threadIdx.x;
#pragma unroll
  for (int j = 0; j < 2; ++j) {
    int v = j * 512 + tid;
    int row = v >> 7;
    int c4 = (v & 127) << 2;
    *(f32x4*)&xs[row][c4] = *(const f32x4*)&src[(size_t)row * 512 + c4];
  }
  __syncthreads();
  const int h = tid;
  const float* wp = W1 + (isenc ? 0 : (size_t)512 * 512) + h;
  float acc[8];
  float init = isenc ? 0.f : b1[h];
#pragma unroll
  for (int r = 0; r < 8; ++r) acc[r] = init;
#pragma unroll 4
  for (int k = 0; k < 512; ++k) {
    float wv = wp[(size_t)k * 512];
#pragma unroll
    for (int r = 0; r < 8; ++r) acc[r] = fmaf(xs[r][k], wv, acc[r]);
  }
  if (isenc) {
#pragma unroll
    for (int r = 0; r < 8; ++r) enc_proj[(size_t)(rows0 + r) * 512 + h] = acc[r];
  } else {
#pragma unroll
    for (int r = 0; r < 8; ++r) decb[(size_t)(rows0 + r) * 512 + h] = f2bf(acc[r]);
  }
}

// ---------------- Pass 2: W2 [512][2048] fp32 -> W2t [2048][512] bf16 ----------------
__global__ __launch_bounds__(256) void w2t_kernel(const float* __restrict__ W2,
                                                  unsigned short* __restrict__ W2t) {
  __shared__ unsigned short tile[32][33];
  int bn = blockIdx.x;
  int bk = blockIdx.y;
  int tx = threadIdx.x & 31;
  int ty = threadIdx.x >> 5;
#pragma unroll
  for (int i = 0; i < 32; i += 8)
    tile[ty + i][tx] = f2bf(W2[(size_t)(bk * 32 + ty + i) * 2048 + bn * 32 + tx]);
  __syncthreads();
#pragma unroll
  for (int i = 0; i < 32; i += 8)
    W2t[(size_t)(bn * 32 + ty + i) * 512 + bk * 32 + tx] = tile[tx][ty + i];
}

// ---------------- Pass 3: H[m][h] = tanh(encp[bt][h] + decb[bu][h]) bf16 ----------------
__global__ __launch_bounds__(256) void h_kernel(
    const float* __restrict__ encp, const unsigned short* __restrict__ decb,
    unsigned short* __restrict__ Hout) {
  int gid = blockIdx.x * 256 + threadIdx.x;
  int m = gid >> 6;
  int hc = (gid & 63) << 3;
  int bt = m >> 7;
  int bu = ((m >> 15) << 7) | (m & 127);
  u16x8 dv = *(const u16x8*)(decb + (size_t)bu * 512 + hc);
  f32x4 e0 = *(const f32x4*)(encp + (size_t)bt * 512 + hc);
  f32x4 e1 = *(const f32x4*)(encp + (size_t)bt * 512 + hc + 4);
  u16x8 hv;
#pragma unroll
  for (int j = 0; j < 4; ++j) hv[j] = f2bf(tanh_fast(bf2f(dv[j]) + e0[j]));
#pragma unroll
  for (int j = 0; j < 4; ++j) hv[4 + j] = f2bf(tanh_fast(bf2f(dv[4 + j]) + e1[j]));
  *(u16x8*)(Hout + (size_t)m * 512 + hc) = hv;
}

// ---------------- Pass 4: persistent BM=256 BN=128 BK=32 GEMM ----------------
// 256 blocks, 512 thr (8 waves, 4M x 2N, wave-tile 64x64). Block (xcd=bid&7,
// slot=bid>>3): ny = slot&15 (fixed), my = xcd*64 + (slot>>4)*32 + t, t=0..31.
// Ring-3 staging slots (24 KB each) + per-wave transpose slices (4352 B) =
// 108.5 KB LDS -> 1 block/CU. Stores of tile t-1: one nt f32x4 store per
// phase of tile t, counted in the vmcnt ledger (steady VMCNT(4)).

__global__ __launch_bounds__(512, 2) void gemmp_kernel(
    const unsigned short* __restrict__ H,     // [131072][512] bf16
    const unsigned short* __restrict__ W2t,   // [2048][512] bf16
    const float* __restrict__ b2,             // [2048]
    float* __restrict__ out) {                // [131072][2048] fp32
  __shared__ __align__(1024) char smem[108544];  // ring 73728 + slices 34816

  const int bid = blockIdx.x;      // 256
  const int xcd = bid & 7;
  const int slt = bid >> 3;        // 0..31
  const int ny = slt & 15;
  const int mybase = xcd * 64 + (slt >> 4) * 32;

  const int tid = threadIdx.x;
  const int lane = tid & 63;
  const int w = tid >> 6;
  const int wm = w >> 1;     // 0..3
  const int wn = w & 1;      // 0..1
  const int fr = lane & 15;
  const int fq = lane >> 4;

  // gl16 source offsets (dest linear, src pre-swizzled: 16B chunk c of row r
  // comes from chunk c^(r&3))
  size_t srcA[2], srcB;
#pragma unroll
  for (int p = 0; p < 2; ++p) {
    int d = p * 8192 + w * 1024 + lane * 16;
    int r = d >> 6;
    int c = (d >> 4) & 3;
    srcA[p] = (size_t)r * 1024 + (size_t)((c ^ (r & 3)) << 4);
  }
  {
    int d = w * 1024 + lane * 16;
    int r = d >> 6;
    int c = (d >> 4) & 3;
    srcB = (size_t)r * 1024 + (size_t)((c ^ (r & 3)) << 4);
  }

  const int swz = (fq ^ (fr & 3)) << 4;
  const int ldsA = (wm * 64 + fr) * 64 + swz;            // + mi*1024
  const int ldsB = 16384 + (wn * 64 + fr) * 64 + swz;    // + ni*1024

  const char* wbase = (const char*)W2t + (size_t)ny * 128 * 1024;
  const int ncol0 = ny * 128 + wn * 64;

  float bv[4];   // bias: per-block constant (ny fixed)
#pragma unroll
  for (int ni = 0; ni < 4; ++ni) bv[ni] = b2[ncol0 + ni * 16 + fr];

  f32x4 acc[4][4], sacc[4][4];
#pragma unroll
  for (int i = 0; i < 4; ++i)
#pragma unroll
    for (int j = 0; j < 4; ++j) acc[i][j] = (f32x4){0.f, 0.f, 0.f, 0.f};

  float* lslice = (float*)(smem + 73728 + w * 4352);   // 16 rows x 68 f32
  const int rrow = lane >> 4;
  const int rcol = (lane & 15) * 4;

#define STAGEG(g)                                                        \
  do {                                                                   \
    int tg_ = (g) >> 4;                                                  \
    int ks_ = (g) & 15;                                                  \
    char* sl_ = smem + ((g) % 3) * 24576;                                \
    const char* ha_ = (const char*)H + ((size_t)(mybase + tg_) << 18);   \
    gl16(ha_ + srcA[0] + ks_ * 64, sl_ + w * 1024);                      \
    gl16(ha_ + srcA[1] + ks_ * 64, sl_ + 8192 + w * 1024);               \
    gl16(wbase + srcB + ks_ * 64, sl_ + 16384 + w * 1024);               \
  } while (0)

  // prologue: batches 0,1
  STAGEG(0);
  STAGEG(1);

#pragma unroll 1
  for (int tt = 0; tt < 32; ++tt) {
    const bool st = tt > 0;
    const size_t prow0 = ((size_t)(mybase + tt - 1) << 8) + wm * 64;  // prev tile
#pragma unroll
    for (int p = 0; p < 16; ++p) {
      const int g = tt * 16 + p;
      // counted waits (in-order vmcnt incl. stores): steady worst-case 4
      if (p == 15) {
        if (tt == 31) { VMCNT(0); } else if (tt <= 1) { VMCNT(3); } else { VMCNT(4); }
      } else {
        if (tt <= 1) { VMCNT(3); } else { VMCNT(4); }
      }
      BAR; MEMPIN;

      const char* As = smem + (g % 3) * 24576;
      bf16x8 a4[4], b4[4];
#pragma unroll
      for (int mi = 0; mi < 4; ++mi) a4[mi] = *(const bf16x8*)(As + ldsA + mi * 1024);
#pragma unroll
      for (int ni = 0; ni < 4; ++ni) b4[ni] = *(const bf16x8*)(As + ldsB + ni * 1024);

      if (g + 2 < 512) STAGEG(g + 2);
      MEMPIN;

      // transpose-write one mi block of prev tile into private slice
      if (st && (p & 3) == 0) {
        const int mi = p >> 2;
#pragma unroll
        for (int ni = 0; ni < 4; ++ni)
#pragma unroll
          for (int r = 0; r < 4; ++r)
            lslice[(fq * 4 + r) * 68 + ni * 16 + fr] = sacc[mi][ni][r];
      }
      LGKM0;

      __builtin_amdgcn_s_setprio(1);
#pragma unroll
      for (int mi = 0; mi < 4; ++mi)
#pragma unroll
        for (int ni = 0; ni < 4; ++ni)
          acc[mi][ni] = __builtin_amdgcn_mfma_f32_16x16x32_bf16(
              a4[mi], b4[ni], acc[mi][ni], 0, 0, 0);
      __builtin_amdgcn_s_setprio(0);

      // one full-line nt store of prev tile per phase
      if (st) {
        const int mi = p >> 2;
        const int row = (p & 3) * 4 + rrow;
        f32x4 v = *(const f32x4*)&lslice[row * 68 + rcol];
        __builtin_nontemporal_store(
            v, (f32x4*)&out[(prow0 + mi * 16 + row) * 2048 + ncol0 + rcol]);
      }
    }
    // save acc (+bias) for store during next tile; reset acc
#pragma unroll
    for (int mi = 0; mi < 4; ++mi)
#pragma unroll
      for (int ni = 0; ni < 4; ++ni) {
#pragma unroll
        for (int r = 0; r < 4; ++r) sacc[mi][ni][r] = acc[mi][ni][r] + bv[ni];
        acc[mi][ni] = (f32x4){0.f, 0.f, 0.f, 0.f};
      }
  }

  // final tile (tt=31) stores
  {
    const size_t prow0 = ((size_t)(mybase + 31) << 8) + wm * 64;
#pragma unroll
    for (int mi = 0; mi < 4; ++mi) {
#pragma unroll
      for (int ni = 0; ni < 4; ++ni)
#pragma unroll
        for (int r = 0; r < 4; ++r)
          lslice[(fq * 4 + r) * 68 + ni * 16 + fr] = sacc[mi][ni][r];
      LGKM0;
#pragma unroll
      for (int j = 0; j < 4; ++j) {
        const int row = j * 4 + rrow;
        f32x4 v = *(const f32x4*)&lslice[row * 68 + rcol];
        __builtin_nontemporal_store(
            v, (f32x4*)&out[(prow0 + mi * 16 + row) * 2048 + ncol0 + rcol]);
      }
    }
  }
#undef STAGEG
}

extern "C" void kernel_launch(void* const* d_in, const int* in_sizes, int n_in,
                              void* d_out, int out_size, void* d_ws, size_t ws_size,
                              hipStream_t stream) {
  const float* enc = (const float*)d_in[0];
  const float* dec = (const float*)d_in[1];
  const float* W1  = (const float*)d_in[2];
  const float* b1  = (const float*)d_in[3];
  const float* W2  = (const float*)d_in[4];
  const float* b2  = (const float*)d_in[5];
  float* out = (float*)d_out;

  char* ws = (char*)d_ws;
  float* enc_proj = (float*)ws;                                    // 2 MB
  unsigned short* decb = (unsigned short*)(ws + (2u << 20));       // 512 KB
  unsigned short* W2t  = (unsigned short*)(ws + (2u << 20) + (512u << 10)); // 2 MB
  unsigned short* Hbuf = (unsigned short*)(ws + (8u << 20));       // 134.25 MB

  proj8_kernel<<<192, 512, 0, stream>>>(enc, dec, W1, b1, enc_proj, decb);
  w2t_kernel<<<dim3(64, 16), 256, 0, stream>>>(W2, W2t);
  h_kernel<<<32768, 256, 0, stream>>>(enc_proj, decb, Hbuf);
  gemmp_kernel<<<256, 512, 0, stream>>>(Hbuf, W2t, b2, out);
}